// Round 1
// baseline (231.027 us; speedup 1.0000x reference)
//
#include <hip/hip_runtime.h>
#include <hip/hip_bf16.h>

#define N_ROWS 16384
#define D_COLS 2048
#define NUM_LABELS 1024
#define NUM_CAMS 8
#define NUM_SEG (NUM_LABELS * NUM_CAMS)   // 8192
#define MAXPER 64                          // max rows per segment we track (true max ~12 for this input)

// ---------------- kernel 1: build per-segment row lists ----------------
__global__ void build_lists_kernel(const int* __restrict__ labels,
                                   const int* __restrict__ cams,
                                   int* __restrict__ counts,
                                   int* __restrict__ lists) {
    int i = blockIdx.x * blockDim.x + threadIdx.x;
    if (i < N_ROWS) {
        int seg = labels[i] * NUM_CAMS + cams[i];
        int pos = atomicAdd(&counts[seg], 1);
        if (pos < MAXPER) lists[seg * MAXPER + pos] = i;
    }
}

__device__ __forceinline__ float smooth_l1(float d) {
    float ad = fabsf(d);
    return ad < 1.0f ? 0.5f * d * d : ad - 0.5f;
}

// ---------------- kernel 2: one block per segment: mean + SmoothL1 ----------------
// 256 threads; thread t owns float4 chunks t and t+256 of the 512 float4s per row.
__global__ __launch_bounds__(256) void seg_loss_kernel(const float* __restrict__ feats,
                                                       const int* __restrict__ counts,
                                                       const int* __restrict__ lists,
                                                       float* __restrict__ loss_acc) {
    int seg = blockIdx.x;
    int tid = threadIdx.x;
    int cnt = counts[seg];
    float local = 0.0f;

    if (cnt > 0) {
        int rows = cnt < MAXPER ? cnt : MAXPER;
        const int* lst = lists + seg * MAXPER;

        float m0x = 0.f, m0y = 0.f, m0z = 0.f, m0w = 0.f;
        float m1x = 0.f, m1y = 0.f, m1z = 0.f, m1w = 0.f;

        // pass 1: accumulate sum over rows (registers only)
        for (int r = 0; r < rows; ++r) {
            int row = lst[r];
            const float4* rp = (const float4*)(feats + (size_t)row * D_COLS);
            float4 a = rp[tid];
            float4 b = rp[tid + 256];
            m0x += a.x; m0y += a.y; m0z += a.z; m0w += a.w;
            m1x += b.x; m1y += b.y; m1z += b.z; m1w += b.w;
        }
        float inv = 1.0f / (float)cnt;   // cnt >= 1 here (matches max(counts,1))
        m0x *= inv; m0y *= inv; m0z *= inv; m0w *= inv;
        m1x *= inv; m1y *= inv; m1z *= inv; m1w *= inv;

        // pass 2: SmoothL1 against the mean (rows hot in L1/L2: only cnt*8KB)
        for (int r = 0; r < rows; ++r) {
            int row = lst[r];
            const float4* rp = (const float4*)(feats + (size_t)row * D_COLS);
            float4 a = rp[tid];
            float4 b = rp[tid + 256];
            local += smooth_l1(a.x - m0x) + smooth_l1(a.y - m0y)
                   + smooth_l1(a.z - m0z) + smooth_l1(a.w - m0w);
            local += smooth_l1(b.x - m1x) + smooth_l1(b.y - m1y)
                   + smooth_l1(b.z - m1z) + smooth_l1(b.w - m1w);
        }
    }

    // block reduction: wave64 shuffle then LDS across 4 waves
    for (int off = 32; off > 0; off >>= 1)
        local += __shfl_down(local, off, 64);

    __shared__ float wsum[4];
    int lane = tid & 63;
    int wid  = tid >> 6;
    if (lane == 0) wsum[wid] = local;
    __syncthreads();
    if (tid == 0) {
        float s = wsum[0] + wsum[1] + wsum[2] + wsum[3];
        if (s != 0.0f) atomicAdd(loss_acc, s);
    }
}

// ---------------- kernel 3: finalize ----------------
__global__ void finalize_kernel(const float* __restrict__ loss_acc, float* __restrict__ out) {
    out[0] = loss_acc[0] * (1.0f / ((float)N_ROWS * (float)D_COLS));
}

extern "C" void kernel_launch(void* const* d_in, const int* in_sizes, int n_in,
                              void* d_out, int out_size, void* d_ws, size_t ws_size,
                              hipStream_t stream) {
    const float* feats = (const float*)d_in[0];
    const int* labels  = (const int*)d_in[1];
    const int* cams    = (const int*)d_in[2];
    float* out = (float*)d_out;

    // workspace layout: counts[NUM_SEG] | acc[1] | lists[NUM_SEG*MAXPER]
    int* counts = (int*)d_ws;
    float* acc  = (float*)(counts + NUM_SEG);
    int* lists  = (int*)(acc + 1);

    // zero counts + acc (lists fully overwritten where read)
    hipMemsetAsync(d_ws, 0, (NUM_SEG + 1) * sizeof(int), stream);

    build_lists_kernel<<<(N_ROWS + 255) / 256, 256, 0, stream>>>(labels, cams, counts, lists);
    seg_loss_kernel<<<NUM_SEG, 256, 0, stream>>>(feats, counts, lists, acc);
    finalize_kernel<<<1, 1, 0, stream>>>(acc, out);
}